// Round 5
// baseline (281.044 us; speedup 1.0000x reference)
//
#include <hip/hip_runtime.h>
#include <hip/hip_bf16.h>

#define HID 16
#define SB_BITS 11
#define SBLK (1 << SB_BITS)            // 2048 nodes per src/dst block
#define SMASK (SBLK - 1)
#define NBMAX 64
#define GSTRIDE 16                     // gcurA: one counter per 64B line
#define PT_THREADS 256
#define PT_K 16
#define PT_EDGES (PT_THREADS * PT_K)   // 4096 edges per partition tile

// ---------------- init: zero cursors (gcurA padded + gcurB) ------------------
__global__ void k_init(int* __restrict__ p, int n) {
    int i = blockIdx.x * blockDim.x + threadIdx.x;
    if (i < n) p[i] = 0;
}

// ---------------- pass A: bin edges by src-block, LDS tile-sort --------------
// payload: (src_loc:11 << 17) | dst:17
__global__ void k_passA(const int* __restrict__ src, const int* __restrict__ dst,
                        unsigned* __restrict__ bucketsA, int* __restrict__ gcurA,
                        int E, int nb, int capA) {
    __shared__ int cnt[NBMAX];
    __shared__ int pos[NBMAX];
    __shared__ int gbase[NBMAX];
    __shared__ unsigned reorder[PT_EDGES];
    __shared__ unsigned char bbk[PT_EDGES];
    int tb = blockIdx.x * PT_EDGES;
    int nE = min(PT_EDGES, E - tb);
    if (threadIdx.x < nb) cnt[threadIdx.x] = 0;
    __syncthreads();
    int kk[PT_K]; int rk[PT_K]; unsigned pk[PT_K];
#pragma unroll
    for (int k = 0; k < PT_K; k++) {
        int e = tb + k * PT_THREADS + threadIdx.x;
        if (e < E) {
            int s = src[e], d = dst[e];
            int b = s >> SB_BITS;
            kk[k] = b;
            pk[k] = ((unsigned)(s & SMASK) << 17) | (unsigned)d;
            rk[k] = atomicAdd(&cnt[b], 1);
        } else kk[k] = -1;
    }
    __syncthreads();
    if (threadIdx.x == 0) {
        int acc = 0;
        for (int b = 0; b < nb; b++) { pos[b] = acc; acc += cnt[b]; }
    }
    __syncthreads();
    if (threadIdx.x < nb && cnt[threadIdx.x] > 0)
        gbase[threadIdx.x] = atomicAdd(&gcurA[threadIdx.x * GSTRIDE], cnt[threadIdx.x]);
    __syncthreads();
#pragma unroll
    for (int k = 0; k < PT_K; k++) {
        if (kk[k] >= 0) {
            int idx = pos[kk[k]] + rk[k];
            reorder[idx] = pk[k];
            bbk[idx] = (unsigned char)kk[k];
        }
    }
    __syncthreads();
    for (int idx = threadIdx.x; idx < nE; idx += PT_THREADS) {
        int b = bbk[idx];
        int g = gbase[b] + (idx - pos[b]);
        if (g < capA) bucketsA[(size_t)b * capA + g] = reorder[idx];
    }
}

// ---------------- pass B: within src-block bucket, bin by dst-block ----------
// payload: (src_loc:11 << 11) | dst_loc:11
__global__ void k_passB(const unsigned* __restrict__ bucketsA, const int* __restrict__ gcurA,
                        unsigned* __restrict__ bucketsB, int* __restrict__ gcurB,
                        int nb, int capA, int capB, int tilesB) {
    int bi = blockIdx.x / tilesB;
    int tile = blockIdx.x - bi * tilesB;
    int cnt_i = min(gcurA[bi * GSTRIDE], capA);
    int tb = tile * PT_EDGES;
    if (tb >= cnt_i) return;
    int nE = min(PT_EDGES, cnt_i - tb);
    __shared__ int cnt[NBMAX];
    __shared__ int pos[NBMAX];
    __shared__ int gbase[NBMAX];
    __shared__ unsigned reorder[PT_EDGES];
    __shared__ unsigned char bbk[PT_EDGES];
    if (threadIdx.x < nb) cnt[threadIdx.x] = 0;
    __syncthreads();
    const unsigned* in = bucketsA + (size_t)bi * capA + tb;
    int kk[PT_K]; int rk[PT_K]; unsigned pk[PT_K];
#pragma unroll
    for (int k = 0; k < PT_K; k++) {
        int e = k * PT_THREADS + threadIdx.x;
        if (e < nE) {
            unsigned p = in[e];
            int d = (int)(p & 0x1FFFFu);
            int j = d >> SB_BITS;
            kk[k] = j;
            pk[k] = ((p >> 17) << 11) | (unsigned)(d & SMASK);
            rk[k] = atomicAdd(&cnt[j], 1);
        } else kk[k] = -1;
    }
    __syncthreads();
    if (threadIdx.x == 0) {
        int acc = 0;
        for (int b = 0; b < nb; b++) { pos[b] = acc; acc += cnt[b]; }
    }
    __syncthreads();
    if (threadIdx.x < nb && cnt[threadIdx.x] > 0)
        gbase[threadIdx.x] = atomicAdd(&gcurB[bi * nb + threadIdx.x], cnt[threadIdx.x]);
    __syncthreads();
#pragma unroll
    for (int k = 0; k < PT_K; k++) {
        if (kk[k] >= 0) {
            int idx = pos[kk[k]] + rk[k];
            reorder[idx] = pk[k];
            bbk[idx] = (unsigned char)kk[k];
        }
    }
    __syncthreads();
    for (int idx = threadIdx.x; idx < nE; idx += PT_THREADS) {
        int j = bbk[idx];
        int g = gbase[j] + (idx - pos[j]);
        if (g < capB) bucketsB[(size_t)(bi * nb + j) * capB + g] = reorder[idx];
    }
}

// ---------------- scalar tile aggregation: all-LDS per edge ------------------
__global__ void __launch_bounds__(256)
k_agg1(const unsigned* __restrict__ bucketsB, const int* __restrict__ gcurB,
       const float* __restrict__ val, float* __restrict__ partial,
       int nb, int capB, int N) {
    __shared__ float sv[SBLK];
    __shared__ float bins[SBLK];
    int i = blockIdx.x / nb, j = blockIdx.x - i * nb;
    int base_i = i << SB_BITS;
    for (int t = threadIdx.x; t < SBLK; t += 256) {
        int nidx = base_i + t;
        sv[t] = (nidx < N) ? val[nidx] : 0.f;
        bins[t] = 0.f;
    }
    __syncthreads();
    int cnt = min(gcurB[blockIdx.x], capB);
    const unsigned* bk = bucketsB + (size_t)blockIdx.x * capB;
    int e = threadIdx.x << 2;
    for (; e + 4 <= cnt; e += 1024) {
        uint4 p = *(const uint4*)(bk + e);
        float v0 = sv[p.x >> SB_BITS];
        float v1 = sv[p.y >> SB_BITS];
        float v2 = sv[p.z >> SB_BITS];
        float v3 = sv[p.w >> SB_BITS];
        atomicAdd(&bins[p.x & SMASK], v0);
        atomicAdd(&bins[p.y & SMASK], v1);
        atomicAdd(&bins[p.z & SMASK], v2);
        atomicAdd(&bins[p.w & SMASK], v3);
    }
    int e1 = min(cnt, e + 4);
    for (int q = e; q < e1; q++) {
        unsigned p = bk[q];
        atomicAdd(&bins[p & SMASK], sv[p >> SB_BITS]);
    }
    __syncthreads();
    float* outp = partial + (size_t)(j * nb + i) * SBLK;
    for (int t = threadIdx.x; t < SBLK; t += 256) outp[t] = bins[t];
}

// ---------------- float2 tile aggregation (separate planes) ------------------
__global__ void __launch_bounds__(256)
k_agg2(const unsigned* __restrict__ bucketsB, const int* __restrict__ gcurB,
       const float* __restrict__ val2, float* __restrict__ partial,
       int nb, int capB, int N) {
    __shared__ float sa[SBLK], sb2[SBLK], ba[SBLK], bb2[SBLK];
    int i = blockIdx.x / nb, j = blockIdx.x - i * nb;
    int base_i = i << SB_BITS;
    const float2* v2 = (const float2*)val2;
    for (int t = threadIdx.x; t < SBLK; t += 256) {
        int nidx = base_i + t;
        float2 v = (nidx < N) ? v2[nidx] : make_float2(0.f, 0.f);
        sa[t] = v.x; sb2[t] = v.y; ba[t] = 0.f; bb2[t] = 0.f;
    }
    __syncthreads();
    int cnt = min(gcurB[blockIdx.x], capB);
    const unsigned* bk = bucketsB + (size_t)blockIdx.x * capB;
    int e = threadIdx.x << 2;
    for (; e + 4 <= cnt; e += 1024) {
        uint4 p = *(const uint4*)(bk + e);
        int s0 = p.x >> SB_BITS, d0 = p.x & SMASK;
        int s1 = p.y >> SB_BITS, d1 = p.y & SMASK;
        int s2 = p.z >> SB_BITS, d2 = p.z & SMASK;
        int s3 = p.w >> SB_BITS, d3 = p.w & SMASK;
        atomicAdd(&ba[d0], sa[s0]); atomicAdd(&bb2[d0], sb2[s0]);
        atomicAdd(&ba[d1], sa[s1]); atomicAdd(&bb2[d1], sb2[s1]);
        atomicAdd(&ba[d2], sa[s2]); atomicAdd(&bb2[d2], sb2[s2]);
        atomicAdd(&ba[d3], sa[s3]); atomicAdd(&bb2[d3], sb2[s3]);
    }
    int e1 = min(cnt, e + 4);
    for (int q = e; q < e1; q++) {
        unsigned p = bk[q];
        int s = p >> SB_BITS, d = p & SMASK;
        atomicAdd(&ba[d], sa[s]); atomicAdd(&bb2[d], sb2[s]);
    }
    __syncthreads();
    float* outp = partial + (size_t)(j * nb + i) * 2 * SBLK;
    for (int t = threadIdx.x; t < SBLK; t += 256) {
        outp[t] = ba[t];
        outp[SBLK + t] = bb2[t];
    }
}

// ---------------- fused reduce(D1) + encode ---------------------------------
// u1 = Wp_rel·wd_rel, u2 = Wp_rel·wd_root, v1 = Wp_root·wd_rel, v2 = Wp_root·wd_root
__global__ void k_encode(const float* __restrict__ x, const float* __restrict__ partial,
                         int nb,
                         const float* __restrict__ ewrel, const float* __restrict__ ewroot,
                         const float* __restrict__ eb,
                         const float* __restrict__ pwrel, const float* __restrict__ pwroot,
                         const float* __restrict__ dwrel, const float* __restrict__ dwroot,
                         float* __restrict__ SAB, float* __restrict__ G1,
                         float* __restrict__ G2, int N) {
    __shared__ float su1[HID], su2[HID], sv1[HID], sv2[HID];
    __shared__ float swr[HID], swo[HID], sbb[HID];
    int t = threadIdx.x;
    if (t < 64) {
        int k = t & 15, w = t >> 4;
        const float* M  = (w < 2) ? pwrel : pwroot;
        const float* vv = ((w & 1) == 0) ? dwrel : dwroot;
        float acc = 0.f;
        for (int h = 0; h < HID; h++) acc += M[k * HID + h] * vv[h];
        if (w == 0) su1[k] = acc;
        else if (w == 1) su2[k] = acc;
        else if (w == 2) sv1[k] = acc;
        else sv2[k] = acc;
    }
    if (t < HID) { swr[t] = ewrel[t]; swo[t] = ewroot[t]; sbb[t] = eb[t]; }
    __syncthreads();
    int i = blockIdx.x * blockDim.x + t;
    if (i >= N) return;
    int j = i >> SB_BITS, dl = i & SMASK;
    float a1 = 0.f;
    for (int c = 0; c < nb; c++)
        a1 += partial[((size_t)(j * nb + c) << SB_BITS) + dl];
    float xi = x[i];
    float sa = 0.f, sb = 0.f, g1 = 0.f, g2 = 0.f;
#pragma unroll
    for (int h = 0; h < HID; h++) {
        float z = fmaxf(fmaf(a1, swr[h], fmaf(xi, swo[h], sbb[h])), 0.f);
        sa = fmaf(z, su1[h], sa);
        sb = fmaf(z, su2[h], sb);
        g1 = fmaf(z, sv1[h], g1);
        g2 = fmaf(z, sv2[h], g2);
    }
    SAB[2 * i] = sa; SAB[2 * i + 1] = sb; G1[i] = g1; G2[i] = g2;
}

// ---------------- fused reduce(D2) + mid ------------------------------------
__global__ void k_mid(const float* __restrict__ partial, int nb,
                      const float* __restrict__ G1, const float* __restrict__ G2,
                      const float* __restrict__ pb, const float* __restrict__ dwrel,
                      const float* __restrict__ dwroot, const float* __restrict__ db,
                      float* __restrict__ BETA, float* __restrict__ R, int N) {
    __shared__ float sc1, sc2, sbd;
    if (threadIdx.x == 0) {
        float c1 = 0.f, c2 = 0.f;
        for (int h = 0; h < HID; h++) { c1 += pb[h] * dwrel[h]; c2 += pb[h] * dwroot[h]; }
        sc1 = c1; sc2 = c2; sbd = db[0];
    }
    __syncthreads();
    int i = blockIdx.x * blockDim.x + threadIdx.x;
    if (i >= N) return;
    int j = i >> SB_BITS, dl = i & SMASK;
    float sa = 0.f, sb = 0.f;
    for (int c = 0; c < nb; c++) {
        const float* pa = partial + ((size_t)(j * nb + c) * 2 << SB_BITS);
        sa += pa[dl];
        sb += pa[SBLK + dl];
    }
    BETA[i] = sa + G1[i] + sc1;
    R[i]    = sb + G2[i] + sc2 + sbd;
}

// ---------------- fused reduce(D3) + final ----------------------------------
__global__ void k_final(const float* __restrict__ partial, int nb,
                        const float* __restrict__ R,
                        float* __restrict__ out, int N) {
    int i = blockIdx.x * blockDim.x + threadIdx.x;
    if (i >= N) return;
    int j = i >> SB_BITS, dl = i & SMASK;
    float s = 0.f;
    for (int c = 0; c < nb; c++)
        s += partial[((size_t)(j * nb + c) << SB_BITS) + dl];
    out[i] = fmaxf(s + R[i], 0.f);
}

// ---------------- launch ----------------
extern "C" void kernel_launch(void* const* d_in, const int* in_sizes, int n_in,
                              void* d_out, int out_size, void* d_ws, size_t ws_size,
                              hipStream_t stream) {
    const float* x      = (const float*)d_in[0];
    const int*   ei     = (const int*)d_in[1];
    const float* ewrel  = (const float*)d_in[2];
    const float* ewroot = (const float*)d_in[3];
    const float* eb     = (const float*)d_in[4];
    const float* pwrel  = (const float*)d_in[5];
    const float* pwroot = (const float*)d_in[6];
    const float* pb     = (const float*)d_in[7];
    const float* dwrel  = (const float*)d_in[8];
    const float* dwroot = (const float*)d_in[9];
    const float* db     = (const float*)d_in[10];
    float* out = (float*)d_out;

    const int N = in_sizes[0];
    const int E = in_sizes[1] / 2;
    const int* src = ei;
    const int* dst = ei + E;

    const int nb = (N + SBLK - 1) >> SB_BITS;            // 49
    int capA = E / nb + 4096; capA = (capA + 1023) & ~1023;   // 69632 = 17*4096
    const int tilesB = (capA + PT_EDGES - 1) / PT_EDGES;       // 17
    int capB = E / (nb * nb) + 300; capB = (capB + 3) & ~3;    // 1632 (~8 sigma slack)

    // workspace layout (4-byte words)
    size_t off = 0;
    int* gcurA = (int*)d_ws;                   off += NBMAX * GSTRIDE;      // 1024
    int* gcurB = (int*)d_ws + off;             off += (size_t)nb * nb;      // 2401
    off = (off + 255) & ~(size_t)255;
    unsigned* bucketsA = (unsigned*)d_ws + off; off += (size_t)nb * capA;
    unsigned* bucketsB = (unsigned*)d_ws + off; off += (size_t)nb * nb * capB;
    float* SAB  = (float*)d_ws + off;          off += (size_t)2 * N;
    float* G1   = (float*)d_ws + off;          off += N;
    float* G2   = (float*)d_ws + off;          off += N;
    float* BETA = (float*)d_ws + off;          off += N;
    float* R    = (float*)d_ws + off;          off += N;
    off = (off + 255) & ~(size_t)255;
    float* partial = (float*)d_ws + off;       // nb*nb*2*SBLK words max (f2)

    const int zeroWords = NBMAX * GSTRIDE + nb * nb;     // gcurA + gcurB contiguous
    const int ntilesA = (E + PT_EDGES - 1) / PT_EDGES;   // 782
    const int nodeBlocks = (N + 255) / 256;

    hipLaunchKernelGGL(k_init, dim3((zeroWords + 255) / 256), dim3(256), 0, stream,
                       gcurA, zeroWords);
    hipLaunchKernelGGL(k_passA, dim3(ntilesA), dim3(PT_THREADS), 0, stream,
                       src, dst, bucketsA, gcurA, E, nb, capA);
    hipLaunchKernelGGL(k_passB, dim3(nb * tilesB), dim3(PT_THREADS), 0, stream,
                       bucketsA, gcurA, bucketsB, gcurB, nb, capA, capB, tilesB);

    // pass 1: tile-aggregate x -> partials; fused reduce in k_encode
    hipLaunchKernelGGL(k_agg1, dim3(nb * nb), dim3(256), 0, stream,
                       bucketsB, gcurB, x, partial, nb, capB, N);
    hipLaunchKernelGGL(k_encode, dim3(nodeBlocks), dim3(256), 0, stream,
                       x, partial, nb, ewrel, ewroot, eb, pwrel, pwroot,
                       dwrel, dwroot, SAB, G1, G2, N);

    // pass 2: tile-aggregate float2(a,b) -> partials; fused reduce in k_mid
    hipLaunchKernelGGL(k_agg2, dim3(nb * nb), dim3(256), 0, stream,
                       bucketsB, gcurB, SAB, partial, nb, capB, N);
    hipLaunchKernelGGL(k_mid, dim3(nodeBlocks), dim3(256), 0, stream,
                       partial, nb, G1, G2, pb, dwrel, dwroot, db, BETA, R, N);

    // pass 3: tile-aggregate BETA -> partials; fused reduce in k_final
    hipLaunchKernelGGL(k_agg1, dim3(nb * nb), dim3(256), 0, stream,
                       bucketsB, gcurB, BETA, partial, nb, capB, N);
    hipLaunchKernelGGL(k_final, dim3(nodeBlocks), dim3(256), 0, stream,
                       partial, nb, R, out, N);
}

// Round 6
// 184.921 us; speedup vs baseline: 1.5198x; 1.5198x over previous
//
#include <hip/hip_runtime.h>
#include <hip/hip_bf16.h>

#define HID 16
#define SB_BITS 11
#define SBLK (1 << SB_BITS)            // 2048 dst per block-range
#define SUBS 128                       // sub-buckets per range (16 dst each)
#define NBMAX 64
#define GSTRIDE 16                     // gcurA: one counter per 64B line
#define PT_THREADS 256
#define PT_K 16
#define PT_EDGES (PT_THREADS * PT_K)   // 4096 edges per partition tile
#define ROWP 65                        // padded slot-row (16 rows of 65 words)

// ---------------- init: zero cursors ----------------
__global__ void k_init(int* __restrict__ p, int n) {
    int i = blockIdx.x * blockDim.x + threadIdx.x;
    if (i < n) p[i] = 0;
}

// ---------------- pass A: bin edges by dst-block; payload (dloc11<<17)|src17 --
__global__ void k_passA(const int* __restrict__ src, const int* __restrict__ dst,
                        unsigned* __restrict__ bucketsA, int* __restrict__ gcurA,
                        int E, int nb, int capA) {
    __shared__ int cnt[NBMAX];
    __shared__ int pos[NBMAX];
    __shared__ int gbase[NBMAX];
    __shared__ unsigned reorder[PT_EDGES];
    __shared__ unsigned char bbk[PT_EDGES];
    int tb = blockIdx.x * PT_EDGES;
    int nE = min(PT_EDGES, E - tb);
    if (threadIdx.x < nb) cnt[threadIdx.x] = 0;
    __syncthreads();
    int kk[PT_K]; int rk[PT_K]; unsigned pk[PT_K];
#pragma unroll
    for (int k = 0; k < PT_K; k++) {
        int e = tb + k * PT_THREADS + threadIdx.x;
        if (e < E) {
            int s = src[e], d = dst[e];
            int b = d >> SB_BITS;
            kk[k] = b;
            pk[k] = ((unsigned)(d & (SBLK - 1)) << 17) | (unsigned)s;
            rk[k] = atomicAdd(&cnt[b], 1);
        } else kk[k] = -1;
    }
    __syncthreads();
    if (threadIdx.x == 0) {
        int acc = 0;
        for (int b = 0; b < nb; b++) { pos[b] = acc; acc += cnt[b]; }
    }
    __syncthreads();
    if (threadIdx.x < nb && cnt[threadIdx.x] > 0)
        gbase[threadIdx.x] = atomicAdd(&gcurA[threadIdx.x * GSTRIDE], cnt[threadIdx.x]);
    __syncthreads();
#pragma unroll
    for (int k = 0; k < PT_K; k++) {
        if (kk[k] >= 0) {
            int idx = pos[kk[k]] + rk[k];
            reorder[idx] = pk[k];
            bbk[idx] = (unsigned char)kk[k];
        }
    }
    __syncthreads();
    for (int idx = threadIdx.x; idx < nE; idx += PT_THREADS) {
        int b = bbk[idx];
        int g = gbase[b] + (idx - pos[b]);
        if (g < capA) bucketsA[(size_t)b * capA + g] = reorder[idx];
    }
}

// ---------------- pass B: bin bucket rows into 16-dst sub-buckets ------------
// out payload: (src17<<4) | d4
__global__ void k_passB(const unsigned* __restrict__ bucketsA, const int* __restrict__ gcurA,
                        unsigned* __restrict__ bucketsB, int* __restrict__ gcurB,
                        int capA, int capSub, int tilesB) {
    int j = blockIdx.x / tilesB;
    int tile = blockIdx.x - j * tilesB;
    int cnt_j = min(gcurA[j * GSTRIDE], capA);
    int tb = tile * PT_EDGES;
    if (tb >= cnt_j) return;                    // block-uniform
    int nE = min(PT_EDGES, cnt_j - tb);
    __shared__ int cnt[SUBS];
    __shared__ int pos[SUBS];
    __shared__ int gb[SUBS];
    __shared__ unsigned reorder[PT_EDGES];
    __shared__ unsigned char bbk[PT_EDGES];
    if (threadIdx.x < SUBS) cnt[threadIdx.x] = 0;
    __syncthreads();
    const unsigned* in = bucketsA + (size_t)j * capA + tb;
    int kk[PT_K]; int rk[PT_K]; unsigned pk[PT_K];
#pragma unroll
    for (int k = 0; k < PT_K; k++) {
        int e = k * PT_THREADS + threadIdx.x;
        if (e < nE) {
            unsigned p = in[e];
            int dloc = (int)(p >> 17);
            int s = dloc >> 4;
            kk[k] = s;
            pk[k] = ((p & 0x1FFFFu) << 4) | (unsigned)(dloc & 15);
            rk[k] = atomicAdd(&cnt[s], 1);
        } else kk[k] = -1;
    }
    __syncthreads();
    if (threadIdx.x == 0) {
        int acc = 0;
        for (int s = 0; s < SUBS; s++) { pos[s] = acc; acc += cnt[s]; }
    }
    __syncthreads();
    if (threadIdx.x < SUBS && cnt[threadIdx.x] > 0)
        gb[threadIdx.x] = atomicAdd(&gcurB[j * SUBS + threadIdx.x], cnt[threadIdx.x]);
    __syncthreads();
#pragma unroll
    for (int k = 0; k < PT_K; k++) {
        if (kk[k] >= 0) {
            int idx = pos[kk[k]] + rk[k];
            reorder[idx] = pk[k];
            bbk[idx] = (unsigned char)kk[k];
        }
    }
    __syncthreads();
    for (int idx = threadIdx.x; idx < nE; idx += PT_THREADS) {
        int s = bbk[idx];
        int g = gb[s] + (idx - pos[s]);
        if (g < capSub) bucketsB[(size_t)(j * SUBS + s) * capSub + g] = reorder[idx];
    }
}

// ---------------- agg f1: one wave per sub-bucket, private slots, no atomics -
__global__ void __launch_bounds__(256)
k_agg1(const unsigned* __restrict__ bucketsB, const int* __restrict__ gcurB,
       const float* __restrict__ val, float* __restrict__ outD,
       int nq, int capSub, int N) {
    __shared__ float P[4 * 16 * ROWP];
    int wv = threadIdx.x >> 6, lane = threadIdx.x & 63;
    int q = blockIdx.x * 4 + wv;
    float* p = P + wv * 16 * ROWP;
#pragma unroll
    for (int d = 0; d < 16; d++) p[d * ROWP + lane] = 0.f;
    if (q < nq) {
        int cnt = min(gcurB[q], capSub);
        const unsigned* bk = bucketsB + (size_t)q * capSub;
        for (int e = lane; e < cnt; e += 64) {
            unsigned pk = bk[e];
            float v = val[pk >> 4];
            int a = (int)(pk & 15) * ROWP + lane;
            p[a] += v;
        }
    }
    __builtin_amdgcn_wave_barrier();
    int d = lane & 15, c0 = (lane >> 4) * 16;
    float s = 0.f;
#pragma unroll
    for (int k = 0; k < 16; k++) s += p[d * ROWP + c0 + k];
    s += __shfl_xor(s, 16);
    s += __shfl_xor(s, 32);
    if (q < nq && lane < 16) {
        int n = q * 16 + lane;
        if (n < N) outD[n] = s;
    }
}

// ---------------- agg f1 + fused final: out = relu(sum + R) ------------------
__global__ void __launch_bounds__(256)
k_agg1f(const unsigned* __restrict__ bucketsB, const int* __restrict__ gcurB,
        const float* __restrict__ val, const float* __restrict__ R,
        float* __restrict__ out, int nq, int capSub, int N) {
    __shared__ float P[4 * 16 * ROWP];
    int wv = threadIdx.x >> 6, lane = threadIdx.x & 63;
    int q = blockIdx.x * 4 + wv;
    float* p = P + wv * 16 * ROWP;
#pragma unroll
    for (int d = 0; d < 16; d++) p[d * ROWP + lane] = 0.f;
    if (q < nq) {
        int cnt = min(gcurB[q], capSub);
        const unsigned* bk = bucketsB + (size_t)q * capSub;
        for (int e = lane; e < cnt; e += 64) {
            unsigned pk = bk[e];
            float v = val[pk >> 4];
            int a = (int)(pk & 15) * ROWP + lane;
            p[a] += v;
        }
    }
    __builtin_amdgcn_wave_barrier();
    int d = lane & 15, c0 = (lane >> 4) * 16;
    float s = 0.f;
#pragma unroll
    for (int k = 0; k < 16; k++) s += p[d * ROWP + c0 + k];
    s += __shfl_xor(s, 16);
    s += __shfl_xor(s, 32);
    if (q < nq && lane < 16) {
        int n = q * 16 + lane;
        if (n < N) out[n] = fmaxf(s + R[n], 0.f);
    }
}

// ---------------- agg f2: two planes, writes float2 D2 -----------------------
__global__ void __launch_bounds__(256)
k_agg2(const unsigned* __restrict__ bucketsB, const int* __restrict__ gcurB,
       const float* __restrict__ val2, float* __restrict__ D2,
       int nq, int capSub, int N) {
    __shared__ float P[4 * 2 * 16 * ROWP];
    int wv = threadIdx.x >> 6, lane = threadIdx.x & 63;
    int q = blockIdx.x * 4 + wv;
    float* pa = P + wv * 2 * 16 * ROWP;
    float* pb = pa + 16 * ROWP;
#pragma unroll
    for (int d = 0; d < 16; d++) { pa[d * ROWP + lane] = 0.f; pb[d * ROWP + lane] = 0.f; }
    const float2* v2 = (const float2*)val2;
    if (q < nq) {
        int cnt = min(gcurB[q], capSub);
        const unsigned* bk = bucketsB + (size_t)q * capSub;
        for (int e = lane; e < cnt; e += 64) {
            unsigned pk = bk[e];
            float2 v = v2[pk >> 4];
            int a = (int)(pk & 15) * ROWP + lane;
            pa[a] += v.x;
            pb[a] += v.y;
        }
    }
    __builtin_amdgcn_wave_barrier();
    int d = lane & 15, c0 = (lane >> 4) * 16;
    float sa = 0.f, sb = 0.f;
#pragma unroll
    for (int k = 0; k < 16; k++) {
        sa += pa[d * ROWP + c0 + k];
        sb += pb[d * ROWP + c0 + k];
    }
    sa += __shfl_xor(sa, 16); sa += __shfl_xor(sa, 32);
    sb += __shfl_xor(sb, 16); sb += __shfl_xor(sb, 32);
    if (q < nq && lane < 16) {
        int n = q * 16 + lane;
        if (n < N) ((float2*)D2)[n] = make_float2(sa, sb);
    }
}

// ---------------- encode: z1 in regs, emit 4 collapsed scalars ---------------
// u1 = Wp_rel·wd_rel, u2 = Wp_rel·wd_root, v1 = Wp_root·wd_rel, v2 = Wp_root·wd_root
__global__ void k_encode(const float* __restrict__ x, const float* __restrict__ D1,
                         const float* __restrict__ ewrel, const float* __restrict__ ewroot,
                         const float* __restrict__ eb,
                         const float* __restrict__ pwrel, const float* __restrict__ pwroot,
                         const float* __restrict__ dwrel, const float* __restrict__ dwroot,
                         float* __restrict__ SAB, float* __restrict__ G1,
                         float* __restrict__ G2, int N) {
    __shared__ float su1[HID], su2[HID], sv1[HID], sv2[HID];
    __shared__ float swr[HID], swo[HID], sbb[HID];
    int t = threadIdx.x;
    if (t < 64) {
        int k = t & 15, w = t >> 4;
        const float* M  = (w < 2) ? pwrel : pwroot;
        const float* vv = ((w & 1) == 0) ? dwrel : dwroot;
        float acc = 0.f;
        for (int h = 0; h < HID; h++) acc += M[k * HID + h] * vv[h];
        if (w == 0) su1[k] = acc;
        else if (w == 1) su2[k] = acc;
        else if (w == 2) sv1[k] = acc;
        else sv2[k] = acc;
    }
    if (t < HID) { swr[t] = ewrel[t]; swo[t] = ewroot[t]; sbb[t] = eb[t]; }
    __syncthreads();
    int i = blockIdx.x * blockDim.x + t;
    if (i >= N) return;
    float a1 = D1[i], xi = x[i];
    float sa = 0.f, sb = 0.f, g1 = 0.f, g2 = 0.f;
#pragma unroll
    for (int h = 0; h < HID; h++) {
        float z = fmaxf(fmaf(a1, swr[h], fmaf(xi, swo[h], sbb[h])), 0.f);
        sa = fmaf(z, su1[h], sa);
        sb = fmaf(z, su2[h], sb);
        g1 = fmaf(z, sv1[h], g1);
        g2 = fmaf(z, sv2[h], g2);
    }
    SAB[2 * i] = sa; SAB[2 * i + 1] = sb; G1[i] = g1; G2[i] = g2;
}

// ---------------- mid: BETA (scattered next) and root term R -----------------
__global__ void k_mid(const float* __restrict__ D2,
                      const float* __restrict__ G1, const float* __restrict__ G2,
                      const float* __restrict__ pb, const float* __restrict__ dwrel,
                      const float* __restrict__ dwroot, const float* __restrict__ db,
                      float* __restrict__ BETA, float* __restrict__ R, int N) {
    __shared__ float sc1, sc2, sbd;
    if (threadIdx.x == 0) {
        float c1 = 0.f, c2 = 0.f;
        for (int h = 0; h < HID; h++) { c1 += pb[h] * dwrel[h]; c2 += pb[h] * dwroot[h]; }
        sc1 = c1; sc2 = c2; sbd = db[0];
    }
    __syncthreads();
    int i = blockIdx.x * blockDim.x + threadIdx.x;
    if (i >= N) return;
    float2 d2 = ((const float2*)D2)[i];
    BETA[i] = d2.x + G1[i] + sc1;
    R[i]    = d2.y + G2[i] + sc2 + sbd;
}

// ---------------- launch ----------------
extern "C" void kernel_launch(void* const* d_in, const int* in_sizes, int n_in,
                              void* d_out, int out_size, void* d_ws, size_t ws_size,
                              hipStream_t stream) {
    const float* x      = (const float*)d_in[0];
    const int*   ei     = (const int*)d_in[1];
    const float* ewrel  = (const float*)d_in[2];
    const float* ewroot = (const float*)d_in[3];
    const float* eb     = (const float*)d_in[4];
    const float* pwrel  = (const float*)d_in[5];
    const float* pwroot = (const float*)d_in[6];
    const float* pb     = (const float*)d_in[7];
    const float* dwrel  = (const float*)d_in[8];
    const float* dwroot = (const float*)d_in[9];
    const float* db     = (const float*)d_in[10];
    float* out = (float*)d_out;

    const int N = in_sizes[0];
    const int E = in_sizes[1] / 2;
    const int* src = ei;
    const int* dst = ei + E;

    const int nb = (N + SBLK - 1) >> SB_BITS;                  // 49
    int capA = ((E / nb + 2048) + PT_EDGES - 1) & ~(PT_EDGES - 1);   // 69632
    const int tilesB = capA / PT_EDGES;                        // 17
    const int nq = nb * SUBS;                                  // 6272 sub-buckets
    int capSub = ((E / nq + 200) + 3) & ~3;                    // ~712 (>8 sigma)

    // workspace layout (4-byte words)
    size_t off = 0;
    int* gcurA = (int*)d_ws;                    off += NBMAX * GSTRIDE;   // 1024
    int* gcurB = (int*)d_ws + off;              off += nq;
    off = (off + 255) & ~(size_t)255;
    unsigned* bucketsA = (unsigned*)d_ws + off; off += (size_t)nb * capA;
    unsigned* bucketsB = (unsigned*)d_ws + off; off += (size_t)nq * capSub;
    float* SAB  = (float*)d_ws + off;           off += (size_t)2 * N;
    float* G1   = (float*)d_ws + off;           off += N;
    float* G2   = (float*)d_ws + off;           off += N;
    float* BETA = (float*)d_ws + off;           off += N;
    float* R    = (float*)d_ws + off;           off += N;
    float* D1   = (float*)d_ws + off;           off += N;
    float* D2   = (float*)d_ws + off;           off += (size_t)2 * N;

    const int zeroWords = NBMAX * GSTRIDE + nq;                 // contiguous
    const int ntilesA = (E + PT_EDGES - 1) / PT_EDGES;          // 782
    const int nodeBlocks = (N + 255) / 256;
    const int aggBlocks = (nq + 3) / 4;                         // 1568

    hipLaunchKernelGGL(k_init, dim3((zeroWords + 255) / 256), dim3(256), 0, stream,
                       gcurA, zeroWords);
    hipLaunchKernelGGL(k_passA, dim3(ntilesA), dim3(PT_THREADS), 0, stream,
                       src, dst, bucketsA, gcurA, E, nb, capA);
    hipLaunchKernelGGL(k_passB, dim3(nb * tilesB), dim3(PT_THREADS), 0, stream,
                       bucketsA, gcurA, bucketsB, gcurB, capA, capSub, tilesB);

    // pass 1: D1 = agg(x)
    hipLaunchKernelGGL(k_agg1, dim3(aggBlocks), dim3(256), 0, stream,
                       bucketsB, gcurB, x, D1, nq, capSub, N);
    hipLaunchKernelGGL(k_encode, dim3(nodeBlocks), dim3(256), 0, stream,
                       x, D1, ewrel, ewroot, eb, pwrel, pwroot,
                       dwrel, dwroot, SAB, G1, G2, N);

    // pass 2: D2 = agg(float2(a,b))
    hipLaunchKernelGGL(k_agg2, dim3(aggBlocks), dim3(256), 0, stream,
                       bucketsB, gcurB, SAB, D2, nq, capSub, N);
    hipLaunchKernelGGL(k_mid, dim3(nodeBlocks), dim3(256), 0, stream,
                       D2, G1, G2, pb, dwrel, dwroot, db, BETA, R, N);

    // pass 3: out = relu(agg(BETA) + R)  (fused final)
    hipLaunchKernelGGL(k_agg1f, dim3(aggBlocks), dim3(256), 0, stream,
                       bucketsB, gcurB, BETA, R, out, nq, capSub, N);
}